// Round 13
// baseline (457.409 us; speedup 1.0000x reference)
//
#include <hip/hip_runtime.h>
#include <hip/hip_bf16.h>

#define BB 2
#define SS 2048
#define DD 256
#define HH 8
#define DKK 32
#define DVV 32
#define LL 3

typedef __hip_bfloat16 bf16;
typedef __attribute__((ext_vector_type(8))) short bfrag;
typedef __attribute__((ext_vector_type(4))) float f4;

__device__ __forceinline__ bfrag ld8(const bf16* p) {
  return *reinterpret_cast<const bfrag*>(p);
}

// ---------------- weight transpose + cast: wts[l][t][n][k] = W_t[l][k][n] ----------------
__global__ __launch_bounds__(256) void cast_weights_k(const float* __restrict__ wq,
                                                      const float* __restrict__ wk,
                                                      const float* __restrict__ wv,
                                                      const float* __restrict__ wfc,
                                                      bf16* __restrict__ wts) {
  int e = blockIdx.x * 256 + threadIdx.x;   // 786432 total
  int mat = e >> 16;                        // 0..11 = l*4 + t
  int t = mat & 3;
  int l = mat >> 2;
  int kk = (e >> 8) & 255;
  int n = e & 255;
  const float* src = (t == 0) ? wq : (t == 1) ? wk : (t == 2) ? wv : wfc;
  float v = src[((size_t)l * 256 + kk) * 256 + n];
  wts[(size_t)mat * 65536 + (size_t)n * 256 + kk] = __float2bfloat16(v);
}

// ---------------- x = seq + positional encoding, cast bf16 ----------------
__global__ __launch_bounds__(256) void pe_add_k(const float* __restrict__ seq,
                                                bf16* __restrict__ xbf) {
  int e = blockIdx.x * 256 + threadIdx.x;   // 1,048,576 total
  int d = e & 255;
  int m = e >> 8;
  int s = m & (SS - 1);
  int i2 = d >> 1;
  float div = __expf((float)(2 * i2) * (-9.210340371976184f / 256.0f));
  float ang = (float)s * div;
  float pe = (d & 1) ? __cosf(ang) : __sinf(ang);
  xbf[e] = __float2bfloat16(seq[e] + pe);
}

// ---------------- Q/K/V projection GEMM: [4096,256] @ [256,256]x3 ----------------
__global__ __launch_bounds__(256) void proj_k(const bf16* __restrict__ xbf,
                                              const bf16* __restrict__ wl,
                                              bf16* __restrict__ q,
                                              bf16* __restrict__ k,
                                              bf16* __restrict__ vt) {
  int lane = threadIdx.x & 63;
  int wv = threadIdx.x >> 6;
  int c = lane & 15, g = lane >> 4;
  int t = blockIdx.y >> 2;
  int n0 = (blockIdx.y & 3) * 64;
  int m0 = blockIdx.x * 64 + wv * 16;
  const bf16* wt = wl + (size_t)t * 65536;
  const bf16* arow = xbf + (size_t)(m0 + c) * 256 + g * 8;
  f4 acc[4];
#pragma unroll
  for (int i = 0; i < 4; ++i) acc[i] = (f4){0.f, 0.f, 0.f, 0.f};
#pragma unroll
  for (int kk = 0; kk < 8; ++kk) {
    bfrag af = ld8(arow + kk * 32);
#pragma unroll
    for (int ns = 0; ns < 4; ++ns) {
      bfrag bfr = ld8(wt + (size_t)(n0 + ns * 16 + c) * 256 + kk * 32 + g * 8);
      acc[ns] = __builtin_amdgcn_mfma_f32_16x16x32_bf16(af, bfr, acc[ns], 0, 0, 0);
    }
  }
#pragma unroll
  for (int ns = 0; ns < 4; ++ns) {
#pragma unroll
    for (int r = 0; r < 4; ++r) {
      int m = m0 + g * 4 + r;
      int n = n0 + ns * 16 + c;
      int b = m >> 11, s = m & (SS - 1);
      int h = n >> 5, d = n & 31;
      bf16 v = __float2bfloat16(acc[ns][r]);
      if (t == 0)      q[((size_t)(b * HH + h) * SS + s) * DKK + d] = v;
      else if (t == 1) k[((size_t)(b * HH + h) * SS + s) * DKK + d] = v;
      else             vt[((size_t)(b * HH + h) * DVV + d) * SS + s] = v;  // V transposed
    }
  }
}

// ---------------- FC GEMM: ctx[4096,256] @ Wfc[256,256] ----------------
__global__ __launch_bounds__(256) void fc_k(const bf16* __restrict__ ctxbf,
                                            const bf16* __restrict__ wt,
                                            bf16* __restrict__ xbf,
                                            float* __restrict__ fout, int wf) {
  int lane = threadIdx.x & 63;
  int wv = threadIdx.x >> 6;
  int c = lane & 15, g = lane >> 4;
  int n0 = blockIdx.y * 64;
  int m0 = blockIdx.x * 64 + wv * 16;
  const bf16* arow = ctxbf + (size_t)(m0 + c) * 256 + g * 8;
  f4 acc[4];
#pragma unroll
  for (int i = 0; i < 4; ++i) acc[i] = (f4){0.f, 0.f, 0.f, 0.f};
#pragma unroll
  for (int kk = 0; kk < 8; ++kk) {
    bfrag af = ld8(arow + kk * 32);
#pragma unroll
    for (int ns = 0; ns < 4; ++ns) {
      bfrag bfr = ld8(wt + (size_t)(n0 + ns * 16 + c) * 256 + kk * 32 + g * 8);
      acc[ns] = __builtin_amdgcn_mfma_f32_16x16x32_bf16(af, bfr, acc[ns], 0, 0, 0);
    }
  }
#pragma unroll
  for (int ns = 0; ns < 4; ++ns) {
#pragma unroll
    for (int r = 0; r < 4; ++r) {
      int m = m0 + g * 4 + r;
      int n = n0 + ns * 16 + c;
      float v = acc[ns][r];
      xbf[(size_t)m * 256 + n] = __float2bfloat16(v);
      if (wf) fout[(size_t)m * 256 + n] = v;
    }
  }
}

// ---------------- FUSED attention, 32 q-rows per wave (2x ILP in the chain) -------
// 1-wave blocks (64 thr), grid (SS/32, B*H). Each K/V frag load feeds TWO MFMAs;
// per-chunk store drain is 8x256B. Halves K/V load traffic and load-issue count
// per output element; per-wave ILP replaces the lost wave/SIMD (fill kernel
// proves stream width, not occupancy, earns store BW).
__global__ __launch_bounds__(64) void attn_full_k(const bf16* __restrict__ q,
                                                  const bf16* __restrict__ k,
                                                  const bf16* __restrict__ vt,
                                                  float* __restrict__ aout,
                                                  bf16* __restrict__ ctxbf) {
  const float C2 = 0.2550350812540738f;  // log2(e)/sqrt(32)
  int lane = threadIdx.x;
  int c = lane & 15, g = lane >> 4;
  int bh = blockIdx.y;
  int b = bh >> 3, h = bh & 7;
  int s0 = blockIdx.x * 32;
  const bf16* qb = q + ((size_t)bh * SS + s0) * DKK;
  const bf16* kb = k + (size_t)bh * SS * DKK;
  const bf16* vb = vt + (size_t)bh * DVV * SS;
  bfrag qf0 = ld8(qb + c * DKK + g * 8);
  bfrag qf1 = ld8(qb + (size_t)(16 + c) * DKK + g * 8);
  const f4 z = {0.f, 0.f, 0.f, 0.f};

  // ---- pass 1: row sums of exp(s) for 32 rows, fully in-register ----
  float sums0[4] = {0.f, 0.f, 0.f, 0.f};
  float sums1[4] = {0.f, 0.f, 0.f, 0.f};
#pragma unroll 4
  for (int kc = 0; kc < SS / 16; ++kc) {
    bfrag kf = ld8(kb + (size_t)(kc * 16 + c) * DKK + g * 8);
    f4 sc0 = __builtin_amdgcn_mfma_f32_16x16x32_bf16(qf0, kf, z, 0, 0, 0);
    f4 sc1 = __builtin_amdgcn_mfma_f32_16x16x32_bf16(qf1, kf, z, 0, 0, 0);
#pragma unroll
    for (int r = 0; r < 4; ++r) {
      sums0[r] += __builtin_amdgcn_exp2f(sc0[r] * C2);
      sums1[r] += __builtin_amdgcn_exp2f(sc1[r] * C2);
    }
  }
#pragma unroll
  for (int mm = 1; mm < 16; mm <<= 1) {
#pragma unroll
    for (int r = 0; r < 4; ++r) {
      sums0[r] += __shfl_xor(sums0[r], mm, 64);
      sums1[r] += __shfl_xor(sums1[r], mm, 64);
    }
  }
  float inv0[4], inv1[4];
#pragma unroll
  for (int r = 0; r < 4; ++r) { inv0[r] = 1.0f / sums0[r]; inv1[r] = 1.0f / sums1[r]; }

  // ---- pass 2: recompute -> {swizzled store tile, PV} ----
  __shared__ __align__(16) float pws[32 * 64];   // 8 KB fp32 store tile
  __shared__ __align__(16) bf16 pbf[32][72];     // 4.5 KB bf16 PV tile (64+8 pad)
  float* arow = aout + ((size_t)bh * SS + s0) * SS;
  f4 acc0 = z, acc1 = z, acc2 = z, acc3 = z;

  for (int j = 0; j < SS / 64; ++j) {
#pragma unroll
    for (int t = 0; t < 4; ++t) {
      bfrag kf = ld8(kb + (size_t)(j * 64 + t * 16 + c) * DKK + g * 8);
      f4 sc0 = __builtin_amdgcn_mfma_f32_16x16x32_bf16(qf0, kf, z, 0, 0, 0);
      f4 sc1 = __builtin_amdgcn_mfma_f32_16x16x32_bf16(qf1, kf, z, 0, 0, 0);
#pragma unroll
      for (int r = 0; r < 4; ++r) {
        int col = t * 16 + c;
        int F = col >> 2;
        {
          float p = __builtin_amdgcn_exp2f(sc0[r] * C2) * inv0[r];
          int row = g * 4 + r;
          pws[row * 64 + ((F ^ row) << 2) + (col & 3)] = p;
          pbf[row][col] = __float2bfloat16(p);
        }
        {
          float p = __builtin_amdgcn_exp2f(sc1[r] * C2) * inv1[r];
          int row = 16 + g * 4 + r;
          pws[row * 64 + ((F ^ (row & 15)) << 2) + (col & 3)] = p;
          pbf[row][col] = __float2bfloat16(p);
        }
      }
    }
    // PV: 2 k-slices x {lo,hi rows} x {d 0-15, 16-31}
#pragma unroll
    for (int ks = 0; ks < 2; ++ks) {
      bfrag vf0 = ld8(vb + (size_t)c * SS + j * 64 + ks * 32 + g * 8);
      bfrag vf1 = ld8(vb + (size_t)(16 + c) * SS + j * 64 + ks * 32 + g * 8);
      bfrag paL = ld8(&pbf[c][ks * 32 + g * 8]);
      acc0 = __builtin_amdgcn_mfma_f32_16x16x32_bf16(paL, vf0, acc0, 0, 0, 0);
      acc1 = __builtin_amdgcn_mfma_f32_16x16x32_bf16(paL, vf1, acc1, 0, 0, 0);
      bfrag paH = ld8(&pbf[16 + c][ks * 32 + g * 8]);
      acc2 = __builtin_amdgcn_mfma_f32_16x16x32_bf16(paH, vf0, acc2, 0, 0, 0);
      acc3 = __builtin_amdgcn_mfma_f32_16x16x32_bf16(paH, vf1, acc3, 0, 0, 0);
    }
    // drain: 8 x 256B-contiguous dwordx4 (4 rows x 64 cols per instr)
#pragma unroll
    for (int qq = 0; qq < 8; ++qq) {
      int row = qq * 4 + g;
      f4 v = *reinterpret_cast<f4*>(&pws[row * 64 + ((c ^ (row & 15)) << 2)]);
      *reinterpret_cast<f4*>(&arow[(size_t)row * SS + j * 64 + (c << 2)]) = v;
    }
  }

  // ---- epilogue: ctx (normalized already) ----
#pragma unroll
  for (int r = 0; r < 4; ++r) {
    {
      int srow = s0 + g * 4 + r;
      size_t base = ((size_t)b * SS + srow) * 256 + h * 32;
      ctxbf[base + c] = __float2bfloat16(acc0[r]);
      ctxbf[base + 16 + c] = __float2bfloat16(acc1[r]);
    }
    {
      int srow = s0 + 16 + g * 4 + r;
      size_t base = ((size_t)b * SS + srow) * 256 + h * 32;
      ctxbf[base + c] = __float2bfloat16(acc2[r]);
      ctxbf[base + 16 + c] = __float2bfloat16(acc3[r]);
    }
  }
}

extern "C" void kernel_launch(void* const* d_in, const int* in_sizes, int n_in,
                              void* d_out, int out_size, void* d_ws, size_t ws_size,
                              hipStream_t stream) {
  (void)in_sizes; (void)n_in; (void)out_size; (void)ws_size;
  const float* seq = (const float*)d_in[0];
  const float* Wq  = (const float*)d_in[1];
  const float* Wk  = (const float*)d_in[2];
  const float* Wv  = (const float*)d_in[3];
  const float* Wfc = (const float*)d_in[4];
  float* out = (float*)d_out;
  float* attns = out + (size_t)BB * SS * DD;

  const size_t MB2 = 2097152;
  char* ws = (char*)d_ws;
  bf16* wts  = (bf16*)(ws);                       // 1.5 MB
  bf16* xbf  = (bf16*)(ws + 1572864);             // 2 MB
  bf16* vtb  = (bf16*)(ws + 1572864 + MB2);       // 2 MB
  bf16* ctxb = (bf16*)(ws + 1572864 + 2 * MB2);   // 2 MB
  bf16* qb   = (bf16*)(ws + 1572864 + 3 * MB2);   // 2 MB
  bf16* kb   = (bf16*)(ws + 1572864 + 4 * MB2);   // 2 MB

  cast_weights_k<<<3072, 256, 0, stream>>>(Wq, Wk, Wv, Wfc, wts);
  pe_add_k<<<4096, 256, 0, stream>>>(seq, xbf);

  for (int l = 0; l < LL; ++l) {
    proj_k<<<dim3(64, 12), 256, 0, stream>>>(xbf, wts + (size_t)l * 4 * 65536, qb, kb, vtb);
    attn_full_k<<<dim3(SS / 32, BB * HH), 64, 0, stream>>>(
        qb, kb, vtb, attns + (size_t)l * BB * HH * SS * SS, ctxb);
    fc_k<<<dim3(64, 4), 256, 0, stream>>>(ctxb, wts + ((size_t)l * 4 + 3) * 65536,
                                          xbf, out, (l == LL - 1) ? 1 : 0);
  }
}

// Round 14
// 345.396 us; speedup vs baseline: 1.3243x; 1.3243x over previous
//
#include <hip/hip_runtime.h>
#include <hip/hip_bf16.h>

#define BB 2
#define SS 2048
#define DD 256
#define HH 8
#define DKK 32
#define DVV 32
#define LL 3

typedef __hip_bfloat16 bf16;
typedef __attribute__((ext_vector_type(8))) short bfrag;
typedef __attribute__((ext_vector_type(4))) float f4;

struct alignas(8) bh4 { bf16 a, b, c, d; };

__device__ __forceinline__ bfrag ld8(const bf16* p) {
  return *reinterpret_cast<const bfrag*>(p);
}

// ---------------- weight transpose + cast: wts[l][t][n][k] = W_t[l][k][n] ----------------
__global__ __launch_bounds__(256) void cast_weights_k(const float* __restrict__ wq,
                                                      const float* __restrict__ wk,
                                                      const float* __restrict__ wv,
                                                      const float* __restrict__ wfc,
                                                      bf16* __restrict__ wts) {
  int e = blockIdx.x * 256 + threadIdx.x;   // 786432 total
  int mat = e >> 16;                        // 0..11 = l*4 + t
  int t = mat & 3;
  int l = mat >> 2;
  int kk = (e >> 8) & 255;
  int n = e & 255;
  const float* src = (t == 0) ? wq : (t == 1) ? wk : (t == 2) ? wv : wfc;
  float v = src[((size_t)l * 256 + kk) * 256 + n];
  wts[(size_t)mat * 65536 + (size_t)n * 256 + kk] = __float2bfloat16(v);
}

// ---------------- x = seq + positional encoding, cast bf16 ----------------
__global__ __launch_bounds__(256) void pe_add_k(const float* __restrict__ seq,
                                                bf16* __restrict__ xbf) {
  int e = blockIdx.x * 256 + threadIdx.x;   // 1,048,576 total
  int d = e & 255;
  int m = e >> 8;
  int s = m & (SS - 1);
  int i2 = d >> 1;
  float div = __expf((float)(2 * i2) * (-9.210340371976184f / 256.0f));
  float ang = (float)s * div;
  float pe = (d & 1) ? __cosf(ang) : __sinf(ang);
  xbf[e] = __float2bfloat16(seq[e] + pe);
}

// ---------------- Q/K/V projection GEMM: [4096,256] @ [256,256]x3 ----------------
__global__ __launch_bounds__(256) void proj_k(const bf16* __restrict__ xbf,
                                              const bf16* __restrict__ wl,
                                              bf16* __restrict__ q,
                                              bf16* __restrict__ k,
                                              bf16* __restrict__ vt) {
  int lane = threadIdx.x & 63;
  int wv = threadIdx.x >> 6;
  int c = lane & 15, g = lane >> 4;
  int t = blockIdx.y >> 2;
  int n0 = (blockIdx.y & 3) * 64;
  int m0 = blockIdx.x * 64 + wv * 16;
  const bf16* wt = wl + (size_t)t * 65536;
  const bf16* arow = xbf + (size_t)(m0 + c) * 256 + g * 8;
  f4 acc[4];
#pragma unroll
  for (int i = 0; i < 4; ++i) acc[i] = (f4){0.f, 0.f, 0.f, 0.f};
#pragma unroll
  for (int kk = 0; kk < 8; ++kk) {
    bfrag af = ld8(arow + kk * 32);
#pragma unroll
    for (int ns = 0; ns < 4; ++ns) {
      bfrag bfr = ld8(wt + (size_t)(n0 + ns * 16 + c) * 256 + kk * 32 + g * 8);
      acc[ns] = __builtin_amdgcn_mfma_f32_16x16x32_bf16(af, bfr, acc[ns], 0, 0, 0);
    }
  }
#pragma unroll
  for (int ns = 0; ns < 4; ++ns) {
#pragma unroll
    for (int r = 0; r < 4; ++r) {
      int m = m0 + g * 4 + r;
      int n = n0 + ns * 16 + c;
      int b = m >> 11, s = m & (SS - 1);
      int h = n >> 5, d = n & 31;
      bf16 v = __float2bfloat16(acc[ns][r]);
      if (t == 0)      q[((size_t)(b * HH + h) * SS + s) * DKK + d] = v;
      else if (t == 1) k[((size_t)(b * HH + h) * SS + s) * DKK + d] = v;
      else             vt[((size_t)(b * HH + h) * DVV + d) * SS + s] = v;  // V transposed
    }
  }
}

// ---------------- FC GEMM: ctx[4096,256] @ Wfc[256,256] ----------------
__global__ __launch_bounds__(256) void fc_k(const bf16* __restrict__ ctxbf,
                                            const bf16* __restrict__ wt,
                                            bf16* __restrict__ xbf,
                                            float* __restrict__ fout, int wf) {
  int lane = threadIdx.x & 63;
  int wv = threadIdx.x >> 6;
  int c = lane & 15, g = lane >> 4;
  int n0 = blockIdx.y * 64;
  int m0 = blockIdx.x * 64 + wv * 16;
  const bf16* arow = ctxbf + (size_t)(m0 + c) * 256 + g * 8;
  f4 acc[4];
#pragma unroll
  for (int i = 0; i < 4; ++i) acc[i] = (f4){0.f, 0.f, 0.f, 0.f};
#pragma unroll
  for (int kk = 0; kk < 8; ++kk) {
    bfrag af = ld8(arow + kk * 32);
#pragma unroll
    for (int ns = 0; ns < 4; ++ns) {
      bfrag bfr = ld8(wt + (size_t)(n0 + ns * 16 + c) * 256 + kk * 32 + g * 8);
      acc[ns] = __builtin_amdgcn_mfma_f32_16x16x32_bf16(af, bfr, acc[ns], 0, 0, 0);
    }
  }
#pragma unroll
  for (int ns = 0; ns < 4; ++ns) {
#pragma unroll
    for (int r = 0; r < 4; ++r) {
      int m = m0 + g * 4 + r;
      int n = n0 + ns * 16 + c;
      float v = acc[ns][r];
      xbf[(size_t)m * 256 + n] = __float2bfloat16(v);
      if (wf) fout[(size_t)m * 256 + n] = v;
    }
  }
}

// ---------------- FUSED attention (R11 base + swapped QK^T, vectorized LDS writes) ----
// mfma(K,Q): lane (c,g) reg r = S[q-row c][k-col g*4+r] -> 4 consecutive k-cols
// per lane. pass1 sums become lane-local (1 acc, 2 shfl_xor); pass2 LDS bounce
// is 1 ds_write_b128 (pws) + 1 ds_write_b64 (pbf) per tile instead of 8 scalar
// writes. pws layout identical to R11 (XOR involution); drain/PV unchanged.
__global__ __launch_bounds__(256) void attn_full_k(const bf16* __restrict__ q,
                                                   const bf16* __restrict__ k,
                                                   const bf16* __restrict__ vt,
                                                   float* __restrict__ aout,
                                                   bf16* __restrict__ ctxbf) {
  const float C2 = 0.2550350812540738f;  // log2(e)/sqrt(32)
  int lane = threadIdx.x & 63;
  int wv = threadIdx.x >> 6;
  int c = lane & 15, g = lane >> 4;
  int bh = blockIdx.y;
  int b = bh >> 3, h = bh & 7;
  int s0 = blockIdx.x * 64 + wv * 16;
  const bf16* qb = q + ((size_t)bh * SS + s0) * DKK;
  const bf16* kb = k + (size_t)bh * SS * DKK;
  const bf16* vb = vt + (size_t)bh * DVV * SS;
  bfrag qf = ld8(qb + c * DKK + g * 8);
  const f4 z = {0.f, 0.f, 0.f, 0.f};

  // ---- pass 1: row sums of exp(s); swapped MFMA -> lane-local accumulation ----
  float sum = 0.f;
#pragma unroll 4
  for (int kc = 0; kc < SS / 16; ++kc) {
    bfrag kf = ld8(kb + (size_t)(kc * 16 + c) * DKK + g * 8);
    f4 sc = __builtin_amdgcn_mfma_f32_16x16x32_bf16(kf, qf, z, 0, 0, 0);
#pragma unroll
    for (int r = 0; r < 4; ++r) sum += __builtin_amdgcn_exp2f(sc[r] * C2);
  }
  sum += __shfl_xor(sum, 16, 64);
  sum += __shfl_xor(sum, 32, 64);
  float inv = 1.0f / sum;   // lane (c,*) holds inv for q-row s0+c

  // ---- pass 2: recompute -> {swizzled fp32 store tile, bf16 PV tile} ----
  __shared__ __align__(16) float pws[4][16 * 64];   // fp32 store-bounce, swizzled
  __shared__ __align__(16) bf16 pbf[4][16][72];     // bf16 PV tile (64 + 8 pad)
  float* pw = pws[wv];
  float* arow = aout + ((size_t)bh * SS + s0) * SS;
  f4 acc0 = z, acc1 = z;

  for (int j = 0; j < SS / 64; ++j) {
#pragma unroll
    for (int t = 0; t < 4; ++t) {
      bfrag kf = ld8(kb + (size_t)(j * 64 + t * 16 + c) * DKK + g * 8);
      f4 sc = __builtin_amdgcn_mfma_f32_16x16x32_bf16(kf, qf, z, 0, 0, 0);
      f4 p;
#pragma unroll
      for (int r = 0; r < 4; ++r) p[r] = __builtin_amdgcn_exp2f(sc[r] * C2) * inv;
      // pws: row c, col4 = t*4+g stored at (t*4+g)^c  (same layout as R11)
      *reinterpret_cast<f4*>(&pw[c * 64 + (((t * 4 + g) ^ c) << 2)]) = p;
      // pbf: row c, cols t*16+g*4 .. +3, one 8B write
      bh4 w = {__float2bfloat16(p[0]), __float2bfloat16(p[1]),
               __float2bfloat16(p[2]), __float2bfloat16(p[3])};
      *reinterpret_cast<bh4*>(&pbf[wv][c][t * 16 + g * 4]) = w;
    }
    // PV: 2 k-slices, A = P rows from pbf, B = V^T rows
#pragma unroll
    for (int ks = 0; ks < 2; ++ks) {
      bfrag pa = ld8(&pbf[wv][c][ks * 32 + g * 8]);
      bfrag vf0 = ld8(vb + (size_t)c * SS + j * 64 + ks * 32 + g * 8);
      acc0 = __builtin_amdgcn_mfma_f32_16x16x32_bf16(pa, vf0, acc0, 0, 0, 0);
      bfrag vf1 = ld8(vb + (size_t)(16 + c) * SS + j * 64 + ks * 32 + g * 8);
      acc1 = __builtin_amdgcn_mfma_f32_16x16x32_bf16(pa, vf1, acc1, 0, 0, 0);
    }
    // drain: 4 x 256B-contiguous dwordx4
#pragma unroll
    for (int qq = 0; qq < 4; ++qq) {
      int row = qq * 4 + g;
      f4 v = *reinterpret_cast<f4*>(&pw[row * 64 + ((c ^ row) << 2)]);
      *reinterpret_cast<f4*>(&arow[(size_t)row * SS + j * 64 + (c << 2)]) = v;
    }
  }

  // ---- epilogue: ctx (already normalized) ----
#pragma unroll
  for (int r = 0; r < 4; ++r) {
    int srow = s0 + g * 4 + r;
    size_t base = ((size_t)b * SS + srow) * 256 + h * 32;
    ctxbf[base + c] = __float2bfloat16(acc0[r]);
    ctxbf[base + 16 + c] = __float2bfloat16(acc1[r]);
  }
}

extern "C" void kernel_launch(void* const* d_in, const int* in_sizes, int n_in,
                              void* d_out, int out_size, void* d_ws, size_t ws_size,
                              hipStream_t stream) {
  (void)in_sizes; (void)n_in; (void)out_size; (void)ws_size;
  const float* seq = (const float*)d_in[0];
  const float* Wq  = (const float*)d_in[1];
  const float* Wk  = (const float*)d_in[2];
  const float* Wv  = (const float*)d_in[3];
  const float* Wfc = (const float*)d_in[4];
  float* out = (float*)d_out;
  float* attns = out + (size_t)BB * SS * DD;

  const size_t MB2 = 2097152;
  char* ws = (char*)d_ws;
  bf16* wts  = (bf16*)(ws);                       // 1.5 MB
  bf16* xbf  = (bf16*)(ws + 1572864);             // 2 MB
  bf16* vtb  = (bf16*)(ws + 1572864 + MB2);       // 2 MB
  bf16* ctxb = (bf16*)(ws + 1572864 + 2 * MB2);   // 2 MB
  bf16* qb   = (bf16*)(ws + 1572864 + 3 * MB2);   // 2 MB
  bf16* kb   = (bf16*)(ws + 1572864 + 4 * MB2);   // 2 MB

  cast_weights_k<<<3072, 256, 0, stream>>>(Wq, Wk, Wv, Wfc, wts);
  pe_add_k<<<4096, 256, 0, stream>>>(seq, xbf);

  for (int l = 0; l < LL; ++l) {
    proj_k<<<dim3(64, 12), 256, 0, stream>>>(xbf, wts + (size_t)l * 4 * 65536, qb, kb, vtb);
    attn_full_k<<<dim3(SS / 64, BB * HH), 256, 0, stream>>>(
        qb, kb, vtb, attns + (size_t)l * BB * HH * SS * SS, ctxb);
    fc_k<<<dim3(64, 4), 256, 0, stream>>>(ctxb, wts + ((size_t)l * 4 + 3) * 65536,
                                          xbf, out, (l == LL - 1) ? 1 : 0);
  }
}

// Round 15
// 342.743 us; speedup vs baseline: 1.3346x; 1.0077x over previous
//
#include <hip/hip_runtime.h>
#include <hip/hip_bf16.h>

#define BB 2
#define SS 2048
#define DD 256
#define HH 8
#define DKK 32
#define DVV 32
#define LL 3

typedef __hip_bfloat16 bf16;
typedef __attribute__((ext_vector_type(8))) short bfrag;
typedef __attribute__((ext_vector_type(4))) float f4;

struct alignas(8) bh4 { bf16 a, b, c, d; };

__device__ __forceinline__ bfrag ld8(const bf16* p) {
  return *reinterpret_cast<const bfrag*>(p);
}

// ---------------- weight transpose + cast: wts[l][t][n][k] = W_t[l][k][n] ----------------
__global__ __launch_bounds__(256) void cast_weights_k(const float* __restrict__ wq,
                                                      const float* __restrict__ wk,
                                                      const float* __restrict__ wv,
                                                      const float* __restrict__ wfc,
                                                      bf16* __restrict__ wts) {
  int e = blockIdx.x * 256 + threadIdx.x;   // 786432 total
  int mat = e >> 16;                        // 0..11 = l*4 + t
  int t = mat & 3;
  int l = mat >> 2;
  int kk = (e >> 8) & 255;
  int n = e & 255;
  const float* src = (t == 0) ? wq : (t == 1) ? wk : (t == 2) ? wv : wfc;
  float v = src[((size_t)l * 256 + kk) * 256 + n];
  wts[(size_t)mat * 65536 + (size_t)n * 256 + kk] = __float2bfloat16(v);
}

// ---------------- x = seq + positional encoding, cast bf16 ----------------
__global__ __launch_bounds__(256) void pe_add_k(const float* __restrict__ seq,
                                                bf16* __restrict__ xbf) {
  int e = blockIdx.x * 256 + threadIdx.x;   // 1,048,576 total
  int d = e & 255;
  int m = e >> 8;
  int s = m & (SS - 1);
  int i2 = d >> 1;
  float div = __expf((float)(2 * i2) * (-9.210340371976184f / 256.0f));
  float ang = (float)s * div;
  float pe = (d & 1) ? __cosf(ang) : __sinf(ang);
  xbf[e] = __float2bfloat16(seq[e] + pe);
}

// ---------------- Q/K/V projection GEMM: [4096,256] @ [256,256]x3 ----------------
__global__ __launch_bounds__(256) void proj_k(const bf16* __restrict__ xbf,
                                              const bf16* __restrict__ wl,
                                              bf16* __restrict__ q,
                                              bf16* __restrict__ k,
                                              bf16* __restrict__ vt) {
  int lane = threadIdx.x & 63;
  int wv = threadIdx.x >> 6;
  int c = lane & 15, g = lane >> 4;
  int t = blockIdx.y >> 2;
  int n0 = (blockIdx.y & 3) * 64;
  int m0 = blockIdx.x * 64 + wv * 16;
  const bf16* wt = wl + (size_t)t * 65536;
  const bf16* arow = xbf + (size_t)(m0 + c) * 256 + g * 8;
  f4 acc[4];
#pragma unroll
  for (int i = 0; i < 4; ++i) acc[i] = (f4){0.f, 0.f, 0.f, 0.f};
#pragma unroll
  for (int kk = 0; kk < 8; ++kk) {
    bfrag af = ld8(arow + kk * 32);
#pragma unroll
    for (int ns = 0; ns < 4; ++ns) {
      bfrag bfr = ld8(wt + (size_t)(n0 + ns * 16 + c) * 256 + kk * 32 + g * 8);
      acc[ns] = __builtin_amdgcn_mfma_f32_16x16x32_bf16(af, bfr, acc[ns], 0, 0, 0);
    }
  }
#pragma unroll
  for (int ns = 0; ns < 4; ++ns) {
#pragma unroll
    for (int r = 0; r < 4; ++r) {
      int m = m0 + g * 4 + r;
      int n = n0 + ns * 16 + c;
      int b = m >> 11, s = m & (SS - 1);
      int h = n >> 5, d = n & 31;
      bf16 v = __float2bfloat16(acc[ns][r]);
      if (t == 0)      q[((size_t)(b * HH + h) * SS + s) * DKK + d] = v;
      else if (t == 1) k[((size_t)(b * HH + h) * SS + s) * DKK + d] = v;
      else             vt[((size_t)(b * HH + h) * DVV + d) * SS + s] = v;  // V transposed
    }
  }
}

// ---------------- FC GEMM: ctx[4096,256] @ Wfc[256,256] ----------------
__global__ __launch_bounds__(256) void fc_k(const bf16* __restrict__ ctxbf,
                                            const bf16* __restrict__ wt,
                                            bf16* __restrict__ xbf,
                                            float* __restrict__ fout, int wf) {
  int lane = threadIdx.x & 63;
  int wv = threadIdx.x >> 6;
  int c = lane & 15, g = lane >> 4;
  int n0 = blockIdx.y * 64;
  int m0 = blockIdx.x * 64 + wv * 16;
  const bf16* arow = ctxbf + (size_t)(m0 + c) * 256 + g * 8;
  f4 acc[4];
#pragma unroll
  for (int i = 0; i < 4; ++i) acc[i] = (f4){0.f, 0.f, 0.f, 0.f};
#pragma unroll
  for (int kk = 0; kk < 8; ++kk) {
    bfrag af = ld8(arow + kk * 32);
#pragma unroll
    for (int ns = 0; ns < 4; ++ns) {
      bfrag bfr = ld8(wt + (size_t)(n0 + ns * 16 + c) * 256 + kk * 32 + g * 8);
      acc[ns] = __builtin_amdgcn_mfma_f32_16x16x32_bf16(af, bfr, acc[ns], 0, 0, 0);
    }
  }
#pragma unroll
  for (int ns = 0; ns < 4; ++ns) {
#pragma unroll
    for (int r = 0; r < 4; ++r) {
      int m = m0 + g * 4 + r;
      int n = n0 + ns * 16 + c;
      float v = acc[ns][r];
      xbf[(size_t)m * 256 + n] = __float2bfloat16(v);
      if (wf) fout[(size_t)m * 256 + n] = v;
    }
  }
}

// ---------------- FUSED attention (R11 base + swapped QK^T, vectorized LDS writes) ----
// mfma(K,Q): lane (c,g) reg r = S[q-row c][k-col g*4+r] -> 4 consecutive k-cols
// per lane. pass1 sums become lane-local (1 acc, 2 shfl_xor); pass2 LDS bounce
// is 1 ds_write_b128 (pws) + 1 ds_write_b64 (pbf) per tile instead of 8 scalar
// writes. pws layout identical to R11 (XOR involution); drain/PV unchanged.
__global__ __launch_bounds__(256) void attn_full_k(const bf16* __restrict__ q,
                                                   const bf16* __restrict__ k,
                                                   const bf16* __restrict__ vt,
                                                   float* __restrict__ aout,
                                                   bf16* __restrict__ ctxbf) {
  const float C2 = 0.2550350812540738f;  // log2(e)/sqrt(32)
  int lane = threadIdx.x & 63;
  int wv = threadIdx.x >> 6;
  int c = lane & 15, g = lane >> 4;
  int bh = blockIdx.y;
  int b = bh >> 3, h = bh & 7;
  int s0 = blockIdx.x * 64 + wv * 16;
  const bf16* qb = q + ((size_t)bh * SS + s0) * DKK;
  const bf16* kb = k + (size_t)bh * SS * DKK;
  const bf16* vb = vt + (size_t)bh * DVV * SS;
  bfrag qf = ld8(qb + c * DKK + g * 8);
  const f4 z = {0.f, 0.f, 0.f, 0.f};

  // ---- pass 1: row sums of exp(s); swapped MFMA -> lane-local accumulation ----
  float sum = 0.f;
#pragma unroll 4
  for (int kc = 0; kc < SS / 16; ++kc) {
    bfrag kf = ld8(kb + (size_t)(kc * 16 + c) * DKK + g * 8);
    f4 sc = __builtin_amdgcn_mfma_f32_16x16x32_bf16(kf, qf, z, 0, 0, 0);
#pragma unroll
    for (int r = 0; r < 4; ++r) sum += __builtin_amdgcn_exp2f(sc[r] * C2);
  }
  sum += __shfl_xor(sum, 16, 64);
  sum += __shfl_xor(sum, 32, 64);
  float inv = 1.0f / sum;   // lane (c,*) holds inv for q-row s0+c

  // ---- pass 2: recompute -> {swizzled fp32 store tile, bf16 PV tile} ----
  __shared__ __align__(16) float pws[4][16 * 64];   // fp32 store-bounce, swizzled
  __shared__ __align__(16) bf16 pbf[4][16][72];     // bf16 PV tile (64 + 8 pad)
  float* pw = pws[wv];
  float* arow = aout + ((size_t)bh * SS + s0) * SS;
  f4 acc0 = z, acc1 = z;

  for (int j = 0; j < SS / 64; ++j) {
#pragma unroll
    for (int t = 0; t < 4; ++t) {
      bfrag kf = ld8(kb + (size_t)(j * 64 + t * 16 + c) * DKK + g * 8);
      f4 sc = __builtin_amdgcn_mfma_f32_16x16x32_bf16(kf, qf, z, 0, 0, 0);
      f4 p;
#pragma unroll
      for (int r = 0; r < 4; ++r) p[r] = __builtin_amdgcn_exp2f(sc[r] * C2) * inv;
      // pws: row c, col4 = t*4+g stored at (t*4+g)^c  (same layout as R11)
      *reinterpret_cast<f4*>(&pw[c * 64 + (((t * 4 + g) ^ c) << 2)]) = p;
      // pbf: row c, cols t*16+g*4 .. +3, one 8B write
      bh4 w = {__float2bfloat16(p[0]), __float2bfloat16(p[1]),
               __float2bfloat16(p[2]), __float2bfloat16(p[3])};
      *reinterpret_cast<bh4*>(&pbf[wv][c][t * 16 + g * 4]) = w;
    }
    // PV: 2 k-slices, A = P rows from pbf, B = V^T rows
#pragma unroll
    for (int ks = 0; ks < 2; ++ks) {
      bfrag pa = ld8(&pbf[wv][c][ks * 32 + g * 8]);
      bfrag vf0 = ld8(vb + (size_t)c * SS + j * 64 + ks * 32 + g * 8);
      acc0 = __builtin_amdgcn_mfma_f32_16x16x32_bf16(pa, vf0, acc0, 0, 0, 0);
      bfrag vf1 = ld8(vb + (size_t)(16 + c) * SS + j * 64 + ks * 32 + g * 8);
      acc1 = __builtin_amdgcn_mfma_f32_16x16x32_bf16(pa, vf1, acc1, 0, 0, 0);
    }
    // drain: 4 x 256B-contiguous dwordx4
#pragma unroll
    for (int qq = 0; qq < 4; ++qq) {
      int row = qq * 4 + g;
      f4 v = *reinterpret_cast<f4*>(&pw[row * 64 + ((c ^ row) << 2)]);
      *reinterpret_cast<f4*>(&arow[(size_t)row * SS + j * 64 + (c << 2)]) = v;
    }
  }

  // ---- epilogue: ctx (already normalized) ----
#pragma unroll
  for (int r = 0; r < 4; ++r) {
    int srow = s0 + g * 4 + r;
    size_t base = ((size_t)b * SS + srow) * 256 + h * 32;
    ctxbf[base + c] = __float2bfloat16(acc0[r]);
    ctxbf[base + 16 + c] = __float2bfloat16(acc1[r]);
  }
}

extern "C" void kernel_launch(void* const* d_in, const int* in_sizes, int n_in,
                              void* d_out, int out_size, void* d_ws, size_t ws_size,
                              hipStream_t stream) {
  (void)in_sizes; (void)n_in; (void)out_size; (void)ws_size;
  const float* seq = (const float*)d_in[0];
  const float* Wq  = (const float*)d_in[1];
  const float* Wk  = (const float*)d_in[2];
  const float* Wv  = (const float*)d_in[3];
  const float* Wfc = (const float*)d_in[4];
  float* out = (float*)d_out;
  float* attns = out + (size_t)BB * SS * DD;

  const size_t MB2 = 2097152;
  char* ws = (char*)d_ws;
  bf16* wts  = (bf16*)(ws);                       // 1.5 MB
  bf16* xbf  = (bf16*)(ws + 1572864);             // 2 MB
  bf16* vtb  = (bf16*)(ws + 1572864 + MB2);       // 2 MB
  bf16* ctxb = (bf16*)(ws + 1572864 + 2 * MB2);   // 2 MB
  bf16* qb   = (bf16*)(ws + 1572864 + 3 * MB2);   // 2 MB
  bf16* kb   = (bf16*)(ws + 1572864 + 4 * MB2);   // 2 MB

  cast_weights_k<<<3072, 256, 0, stream>>>(Wq, Wk, Wv, Wfc, wts);
  pe_add_k<<<4096, 256, 0, stream>>>(seq, xbf);

  for (int l = 0; l < LL; ++l) {
    proj_k<<<dim3(64, 12), 256, 0, stream>>>(xbf, wts + (size_t)l * 4 * 65536, qb, kb, vtb);
    attn_full_k<<<dim3(SS / 64, BB * HH), 256, 0, stream>>>(
        qb, kb, vtb, attns + (size_t)l * BB * HH * SS * SS, ctxb);
    fc_k<<<dim3(64, 4), 256, 0, stream>>>(ctxb, wts + ((size_t)l * 4 + 3) * 65536,
                                          xbf, out, (l == LL - 1) ? 1 : 0);
  }
}